// Round 2
// baseline (11810.414 us; speedup 1.0000x reference)
//
#include <hip/hip_runtime.h>
#include <hip/hip_bf16.h>

#define DD 256
#define HH 8
#define DH 32
#define SS 512
#define MM 1024
#define BB 16
#define FF 1024
#define LL 6
#define VV 3000

// Mixed-dtype load: bf==1 -> bf16, bf==0 -> fp32. Branch (not select) so the
// wrong-width load is never issued (OOB safety).
__device__ __forceinline__ float ldx(const void* p, size_t i, int bf) {
    if (bf) return __bfloat162float(((const __hip_bfloat16*)p)[i]);
    return ((const float*)p)[i];
}

// dtype detector: writes 1 if buffer is bf16, 0 if fp32.
// True-bf16 N(0,0.02^2) data: every 16-bit half has exponent in [90,140] or is
// +/-0 (P(miss) ~ 1e-7). fp32 data: low half-words are random mantissa bits,
// P(all 512 halves pass) ~ 0.2^256 ~ 1e-180.
__global__ void detect_k(const unsigned int* __restrict__ w, int* __restrict__ flag) {
    int t = threadIdx.x;
    unsigned int v = w[t];
    int ok = 1;
#pragma unroll
    for (int h = 0; h < 2; ++h) {
        unsigned int hw = (v >> (16 * h)) & 0xFFFFu;
        unsigned int e = (hw >> 7) & 0xFFu;
        if (!((e >= 90u && e <= 140u) || (hw & 0x7FFFu) == 0u)) ok = 0;
    }
    __shared__ int allok;
    if (t == 0) allok = 1;
    __syncthreads();
    if (!ok) atomicAnd(&allok, 0);
    __syncthreads();
    if (t == 0) *flag = allok;
}

// x = input_embed[seq] + pos_embed
__global__ void embed_k(const int* __restrict__ seq,
                        const void* __restrict__ emb,
                        const void* __restrict__ pos,
                        float* __restrict__ x,
                        const int* __restrict__ flagp) {
    int bf = *flagp;
    int row = blockIdx.x;           // b*512 + s
    int d = threadIdx.x;            // 0..255
    int s = row & (SS - 1);
    int b = row >> 9;
    int tok = seq[b * SS + s];
    x[(size_t)row * DD + d] = ldx(emb, (size_t)tok * DD + d, bf) +
                              ldx(pos, (size_t)s * DD + d, bf);
}

// C[M,N] = A[M,K] @ B[K,N] (+bias)(+relu). A: AEXT?flag-dtype:fp32 workspace.
// Weights/bias passed as element OFFSETS from byte base (width resolved by flag).
// 64x64 tile, 256 threads, 4x4 per thread, TK=16. M,N,K multiples of 64/16.
template <int AEXT>
__global__ void gemm_k(const void* __restrict__ A,
                       const char* __restrict__ Bbase, size_t boff,
                       const char* __restrict__ biasbase, size_t biasoff, int hasbias,
                       float* __restrict__ C,
                       int M, int N, int K, int relu,
                       const int* __restrict__ flagp) {
    int bf = *flagp;
    const void* Bw = Bbase + boff * (bf ? 2 : 4);
    const void* bias = hasbias ? (const void*)(biasbase + biasoff * (bf ? 2 : 4)) : nullptr;
    __shared__ float As[16][65];
    __shared__ float Bs[16][65];
    int tid = threadIdx.x;
    int n0 = blockIdx.x * 64;
    int m0 = blockIdx.y * 64;
    int ty4 = (tid >> 4) << 2;
    int tx4 = (tid & 15) << 2;
    float acc[4][4] = {{0.f}};

    for (int k0 = 0; k0 < K; k0 += 16) {
#pragma unroll
        for (int r = 0; r < 4; ++r) {
            int i = r * 256 + tid;
            int ma = i >> 4, ka = i & 15;
            As[ka][ma] = AEXT ? ldx(A, (size_t)(m0 + ma) * K + k0 + ka, bf)
                              : ((const float*)A)[(size_t)(m0 + ma) * K + k0 + ka];
            int kb = i >> 6, nb = i & 63;
            Bs[kb][nb] = ldx(Bw, (size_t)(k0 + kb) * N + n0 + nb, bf);
        }
        __syncthreads();
#pragma unroll
        for (int k = 0; k < 16; ++k) {
            float a0 = As[k][ty4 + 0], a1 = As[k][ty4 + 1];
            float a2 = As[k][ty4 + 2], a3 = As[k][ty4 + 3];
            float b0 = Bs[k][tx4 + 0], b1 = Bs[k][tx4 + 1];
            float b2 = Bs[k][tx4 + 2], b3 = Bs[k][tx4 + 3];
            acc[0][0] += a0 * b0; acc[0][1] += a0 * b1; acc[0][2] += a0 * b2; acc[0][3] += a0 * b3;
            acc[1][0] += a1 * b0; acc[1][1] += a1 * b1; acc[1][2] += a1 * b2; acc[1][3] += a1 * b3;
            acc[2][0] += a2 * b0; acc[2][1] += a2 * b1; acc[2][2] += a2 * b2; acc[2][3] += a2 * b3;
            acc[3][0] += a3 * b0; acc[3][1] += a3 * b1; acc[3][2] += a3 * b2; acc[3][3] += a3 * b3;
        }
        __syncthreads();
    }
#pragma unroll
    for (int i = 0; i < 4; ++i) {
#pragma unroll
        for (int j = 0; j < 4; ++j) {
            float v = acc[i][j];
            if (bias) v += ldx(bias, n0 + tx4 + j, bf);
            if (relu) v = fmaxf(v, 0.f);
            C[(size_t)(m0 + ty4 + i) * N + n0 + tx4 + j] = v;
        }
    }
}

// out[M,N] = A[M,K] @ E^T + bias; store dtype per flag.
__global__ void gemm_out_k(const float* __restrict__ A,
                           const void* __restrict__ E,   // [N,K] = [V,D]
                           const void* __restrict__ bias,
                           void* __restrict__ Cout,
                           int M, int N, int K,
                           const int* __restrict__ flagp) {
    int bf = *flagp;
    __shared__ float As[16][65];
    __shared__ float Bs[16][65];
    int tid = threadIdx.x;
    int n0 = blockIdx.x * 64;
    int m0 = blockIdx.y * 64;
    int ty4 = (tid >> 4) << 2;
    int tx4 = (tid & 15) << 2;
    float acc[4][4] = {{0.f}};

    for (int k0 = 0; k0 < K; k0 += 16) {
#pragma unroll
        for (int r = 0; r < 4; ++r) {
            int i = r * 256 + tid;
            int ma = i >> 4, ka = i & 15;
            As[ka][ma] = A[(size_t)(m0 + ma) * K + k0 + ka];
            int nb = i >> 4, kb = i & 15;
            int col = n0 + nb;
            Bs[kb][nb] = (col < N) ? ldx(E, (size_t)col * K + k0 + kb, bf) : 0.f;
        }
        __syncthreads();
#pragma unroll
        for (int k = 0; k < 16; ++k) {
            float a0 = As[k][ty4 + 0], a1 = As[k][ty4 + 1];
            float a2 = As[k][ty4 + 2], a3 = As[k][ty4 + 3];
            float b0 = Bs[k][tx4 + 0], b1 = Bs[k][tx4 + 1];
            float b2 = Bs[k][tx4 + 2], b3 = Bs[k][tx4 + 3];
            acc[0][0] += a0 * b0; acc[0][1] += a0 * b1; acc[0][2] += a0 * b2; acc[0][3] += a0 * b3;
            acc[1][0] += a1 * b0; acc[1][1] += a1 * b1; acc[1][2] += a1 * b2; acc[1][3] += a1 * b3;
            acc[2][0] += a2 * b0; acc[2][1] += a2 * b1; acc[2][2] += a2 * b2; acc[2][3] += a2 * b3;
            acc[3][0] += a3 * b0; acc[3][1] += a3 * b1; acc[3][2] += a3 * b2; acc[3][3] += a3 * b3;
        }
        __syncthreads();
    }
#pragma unroll
    for (int i = 0; i < 4; ++i) {
#pragma unroll
        for (int j = 0; j < 4; ++j) {
            int col = n0 + tx4 + j;
            if (col < N) {
                float v = acc[i][j] + ldx(bias, col, bf);
                size_t oi = (size_t)(m0 + ty4 + i) * N + col;
                if (bf) ((__hip_bfloat16*)Cout)[oi] = __float2bfloat16(v);
                else    ((float*)Cout)[oi] = v;
            }
        }
    }
}

// attention: one thread per (b,h,q), online softmax. All operands fp32 ws.
__global__ void attn_k(const float* __restrict__ Q,
                       const float* __restrict__ Kb,
                       const float* __restrict__ Vb,
                       float* __restrict__ O,
                       int Sk, int causal) {
    int t = blockIdx.x * 256 + threadIdx.x;
    int q = t & (SS - 1);
    int bh = t >> 9;
    int h = bh & (HH - 1);
    int b = bh >> 3;
    const float* qp = Q + (size_t)(b * SS + q) * DD + h * DH;
    float qr[DH];
#pragma unroll
    for (int i = 0; i < DH; ++i) qr[i] = qp[i];
    float m = -1e30f, l = 0.f;
    float o[DH];
#pragma unroll
    for (int i = 0; i < DH; ++i) o[i] = 0.f;
    int jmax = causal ? q : (Sk - 1);
    const float scale = 0.17677669529663689f;  // 1/sqrt(32)
    for (int j = 0; j <= jmax; ++j) {
        const float* kp = Kb + (size_t)(b * Sk + j) * DD + h * DH;
        float s = 0.f;
#pragma unroll
        for (int i = 0; i < DH; ++i) s += qr[i] * kp[i];
        s *= scale;
        const float* vp = Vb + (size_t)(b * Sk + j) * DD + h * DH;
        if (s <= m) {
            float p = __expf(s - m);
            l += p;
#pragma unroll
            for (int i = 0; i < DH; ++i) o[i] += p * vp[i];
        } else {
            float alpha = __expf(m - s);  // first iter: exp(-huge) = 0
            m = s;
            l = l * alpha + 1.f;
#pragma unroll
            for (int i = 0; i < DH; ++i) o[i] = o[i] * alpha + vp[i];
        }
    }
    float inv = 1.f / l;
    float* op = O + (size_t)(b * SS + q) * DD + h * DH;
#pragma unroll
    for (int i = 0; i < DH; ++i) op[i] = o[i] * inv;
}

// x = LN(x + h); gamma/beta as element offsets from byte bases.
__global__ void add_ln_k(float* __restrict__ x,
                         const float* __restrict__ hbuf,
                         const char* __restrict__ gbase, size_t goff,
                         const char* __restrict__ bbase, size_t boff,
                         const int* __restrict__ flagp) {
    int bf = *flagp;
    const void* g = gbase + goff * (bf ? 2 : 4);
    const void* bb = bbase + boff * (bf ? 2 : 4);
    int row = blockIdx.x;
    int d = threadIdx.x;                 // 256 threads, one per element
    float v = x[(size_t)row * DD + d];
    if (hbuf) v += hbuf[(size_t)row * DD + d];
    float s = v, s2 = v * v;
#pragma unroll
    for (int off = 32; off > 0; off >>= 1) {
        s += __shfl_down(s, off);
        s2 += __shfl_down(s2, off);
    }
    __shared__ float sh[8];
    int w = d >> 6;
    if ((d & 63) == 0) { sh[w] = s; sh[4 + w] = s2; }
    __syncthreads();
    if (d == 0) {
        sh[0] = sh[0] + sh[1] + sh[2] + sh[3];
        sh[4] = sh[4] + sh[5] + sh[6] + sh[7];
    }
    __syncthreads();
    float mu = sh[0] * (1.f / DD);
    float var = fmaxf(sh[4] * (1.f / DD) - mu * mu, 0.f);
    float inv = rsqrtf(var + 1e-5f);
    x[(size_t)row * DD + d] = (v - mu) * inv * ldx(g, d, bf) + ldx(bb, d, bf);
}

extern "C" void kernel_launch(void* const* d_in, const int* in_sizes, int n_in,
                              void* d_out, int out_size, void* d_ws, size_t ws_size,
                              hipStream_t stream) {
    const void* encoded     = d_in[0];
    const int*  seq         = (const int*)d_in[1];
    const void* input_embed = d_in[2];
    const void* pos_embed   = d_in[3];
    const void* output_bias = d_in[4];
    const char* sa_qkv      = (const char*)d_in[5];
    const char* sa_o        = (const char*)d_in[6];
    const char* ca_q        = (const char*)d_in[7];
    const char* ca_kv       = (const char*)d_in[8];
    const char* ca_o        = (const char*)d_in[9];
    const char* ffn_w1      = (const char*)d_in[10];
    const char* ffn_b1      = (const char*)d_in[11];
    const char* ffn_w2      = (const char*)d_in[12];
    const char* ffn_b2      = (const char*)d_in[13];
    const char* ln_g        = (const char*)d_in[14];
    const char* ln_b        = (const char*)d_in[15];
    const char* fin_g       = (const char*)d_in[16];
    const char* fin_b       = (const char*)d_in[17];

    const size_t NTOK = (size_t)BB * SS;          // 8192

    int* flag = (int*)d_ws;
    float* x  = (float*)d_ws + 64;                // 8192*256
    float* Qb = x  + NTOK * DD;                   // 8192*256
    float* Kb = Qb + NTOK * DD;                   // 16384*256
    float* Vb = Kb + (size_t)BB * MM * DD;        // 16384*256
    float* Ob = Vb + (size_t)BB * MM * DD;        // 8192*256
    float* Tb = Qb;                               // alias: Qb dead after attn
    float* Hb = Kb;                               // alias: Kb/Vb dead after cross-attn
    // total ws: ~56 MiB

    detect_k<<<1, 256, 0, stream>>>((const unsigned int*)input_embed, flag);
    embed_k<<<NTOK, 256, 0, stream>>>(seq, input_embed, pos_embed, x, flag);

    dim3 g1(DD / 64, NTOK / 64);                  // (4,128)
    dim3 g2(DD / 64, (BB * MM) / 64);             // (4,256)
    dim3 g3(FF / 64, NTOK / 64);                  // (16,128)

    for (int l = 0; l < LL; ++l) {
        size_t oQKV = (size_t)l * 3 * DD * DD;
        size_t oO   = (size_t)l * DD * DD;        // sa_o / ca_q / ca_o layer offset
        size_t oCKV = (size_t)l * 2 * DD * DD;
        size_t oW1  = (size_t)l * DD * FF;
        size_t oB1  = (size_t)l * FF;
        size_t oW2  = (size_t)l * FF * DD;
        size_t oB2  = (size_t)l * DD;
        size_t oG   = (size_t)l * 3 * DD;

        // --- self attention ---
        gemm_k<0><<<g1, 256, 0, stream>>>(x, sa_qkv, oQKV,              nullptr, 0, 0, Qb, (int)NTOK, DD, DD, 0, flag);
        gemm_k<0><<<g1, 256, 0, stream>>>(x, sa_qkv, oQKV + DD * DD,    nullptr, 0, 0, Kb, (int)NTOK, DD, DD, 0, flag);
        gemm_k<0><<<g1, 256, 0, stream>>>(x, sa_qkv, oQKV + 2 * DD * DD, nullptr, 0, 0, Vb, (int)NTOK, DD, DD, 0, flag);
        attn_k<<<(BB * HH * SS) / 256, 256, 0, stream>>>(Qb, Kb, Vb, Ob, SS, 1);
        gemm_k<0><<<g1, 256, 0, stream>>>(Ob, sa_o, oO, nullptr, 0, 0, Tb, (int)NTOK, DD, DD, 0, flag);
        add_ln_k<<<NTOK, 256, 0, stream>>>(x, Tb, ln_g, oG, ln_b, oG, flag);
        // --- cross attention ---
        gemm_k<0><<<g1, 256, 0, stream>>>(x, ca_q, oO, nullptr, 0, 0, Qb, (int)NTOK, DD, DD, 0, flag);
        gemm_k<1><<<g2, 256, 0, stream>>>(encoded, ca_kv, oCKV,           nullptr, 0, 0, Kb, BB * MM, DD, DD, 0, flag);
        gemm_k<1><<<g2, 256, 0, stream>>>(encoded, ca_kv, oCKV + DD * DD, nullptr, 0, 0, Vb, BB * MM, DD, DD, 0, flag);
        attn_k<<<(BB * HH * SS) / 256, 256, 0, stream>>>(Qb, Kb, Vb, Ob, MM, 0);
        gemm_k<0><<<g1, 256, 0, stream>>>(Ob, ca_o, oO, nullptr, 0, 0, Tb, (int)NTOK, DD, DD, 0, flag);
        add_ln_k<<<NTOK, 256, 0, stream>>>(x, Tb, ln_g, oG + DD, ln_b, oG + DD, flag);
        // --- FFN ---
        gemm_k<0><<<g3, 256, 0, stream>>>(x, ffn_w1, oW1, ffn_b1, oB1, 1, Hb, (int)NTOK, FF, DD, 1, flag);
        gemm_k<0><<<g1, 256, 0, stream>>>(Hb, ffn_w2, oW2, ffn_b2, oB2, 1, Tb, (int)NTOK, DD, FF, 0, flag);
        add_ln_k<<<NTOK, 256, 0, stream>>>(x, Tb, ln_g, oG + 2 * DD, ln_b, oG + 2 * DD, flag);
    }
    // final norm + shared-embedding logits
    add_ln_k<<<NTOK, 256, 0, stream>>>(x, nullptr, fin_g, 0, fin_b, 0, flag);
    dim3 g4((VV + 63) / 64, NTOK / 64);           // (47,128)
    gemm_out_k<<<g4, 256, 0, stream>>>(x, input_embed, output_bias, d_out, (int)NTOK, VV, DD, flag);
}

// Round 3
// 9759.419 us; speedup vs baseline: 1.2102x; 1.2102x over previous
//
#include <hip/hip_runtime.h>
#include <hip/hip_bf16.h>

#define DD 256
#define HH 8
#define DH 32
#define SS 512
#define MM 1024
#define BB 16
#define FF 1024
#define LL 6
#define VV 3000
#define QT 256   // q rows per attention block
#define TJ 64    // K/V rows staged per LDS tile

// Mixed-dtype load: bf==1 -> bf16, bf==0 -> fp32. Branch (not select) so the
// wrong-width load is never issued (OOB safety).
__device__ __forceinline__ float ldx(const void* p, size_t i, int bf) {
    if (bf) return __bfloat162float(((const __hip_bfloat16*)p)[i]);
    return ((const float*)p)[i];
}

// dtype detector: writes 1 if buffer is bf16, 0 if fp32.
__global__ void detect_k(const unsigned int* __restrict__ w, int* __restrict__ flag) {
    int t = threadIdx.x;
    unsigned int v = w[t];
    int ok = 1;
#pragma unroll
    for (int h = 0; h < 2; ++h) {
        unsigned int hw = (v >> (16 * h)) & 0xFFFFu;
        unsigned int e = (hw >> 7) & 0xFFu;
        if (!((e >= 90u && e <= 140u) || (hw & 0x7FFFu) == 0u)) ok = 0;
    }
    __shared__ int allok;
    if (t == 0) allok = 1;
    __syncthreads();
    if (!ok) atomicAnd(&allok, 0);
    __syncthreads();
    if (t == 0) *flag = allok;
}

// x = input_embed[seq] + pos_embed
__global__ void embed_k(const int* __restrict__ seq,
                        const void* __restrict__ emb,
                        const void* __restrict__ pos,
                        float* __restrict__ x,
                        const int* __restrict__ flagp) {
    int bf = *flagp;
    int row = blockIdx.x;           // b*512 + s
    int d = threadIdx.x;            // 0..255
    int s = row & (SS - 1);
    int b = row >> 9;
    int tok = seq[b * SS + s];
    x[(size_t)row * DD + d] = ldx(emb, (size_t)tok * DD + d, bf) +
                              ldx(pos, (size_t)s * DD + d, bf);
}

// C[M,N] = A[M,K] @ B[K,N] (+bias)(+relu). A: AEXT?flag-dtype:fp32 workspace.
template <int AEXT>
__global__ void gemm_k(const void* __restrict__ A,
                       const char* __restrict__ Bbase, size_t boff,
                       const char* __restrict__ biasbase, size_t biasoff, int hasbias,
                       float* __restrict__ C,
                       int M, int N, int K, int relu,
                       const int* __restrict__ flagp) {
    int bf = *flagp;
    const void* Bw = Bbase + boff * (bf ? 2 : 4);
    const void* bias = hasbias ? (const void*)(biasbase + biasoff * (bf ? 2 : 4)) : nullptr;
    __shared__ float As[16][65];
    __shared__ float Bs[16][65];
    int tid = threadIdx.x;
    int n0 = blockIdx.x * 64;
    int m0 = blockIdx.y * 64;
    int ty4 = (tid >> 4) << 2;
    int tx4 = (tid & 15) << 2;
    float acc[4][4] = {{0.f}};

    for (int k0 = 0; k0 < K; k0 += 16) {
#pragma unroll
        for (int r = 0; r < 4; ++r) {
            int i = r * 256 + tid;
            int ma = i >> 4, ka = i & 15;
            As[ka][ma] = AEXT ? ldx(A, (size_t)(m0 + ma) * K + k0 + ka, bf)
                              : ((const float*)A)[(size_t)(m0 + ma) * K + k0 + ka];
            int kb = i >> 6, nb = i & 63;
            Bs[kb][nb] = ldx(Bw, (size_t)(k0 + kb) * N + n0 + nb, bf);
        }
        __syncthreads();
#pragma unroll
        for (int k = 0; k < 16; ++k) {
            float a0 = As[k][ty4 + 0], a1 = As[k][ty4 + 1];
            float a2 = As[k][ty4 + 2], a3 = As[k][ty4 + 3];
            float b0 = Bs[k][tx4 + 0], b1 = Bs[k][tx4 + 1];
            float b2 = Bs[k][tx4 + 2], b3 = Bs[k][tx4 + 3];
            acc[0][0] += a0 * b0; acc[0][1] += a0 * b1; acc[0][2] += a0 * b2; acc[0][3] += a0 * b3;
            acc[1][0] += a1 * b0; acc[1][1] += a1 * b1; acc[1][2] += a1 * b2; acc[1][3] += a1 * b3;
            acc[2][0] += a2 * b0; acc[2][1] += a2 * b1; acc[2][2] += a2 * b2; acc[2][3] += a2 * b3;
            acc[3][0] += a3 * b0; acc[3][1] += a3 * b1; acc[3][2] += a3 * b2; acc[3][3] += a3 * b3;
        }
        __syncthreads();
    }
#pragma unroll
    for (int i = 0; i < 4; ++i) {
#pragma unroll
        for (int j = 0; j < 4; ++j) {
            float v = acc[i][j];
            if (bias) v += ldx(bias, n0 + tx4 + j, bf);
            if (relu) v = fmaxf(v, 0.f);
            C[(size_t)(m0 + ty4 + i) * N + n0 + tx4 + j] = v;
        }
    }
}

// out[M,N] = A[M,K] @ E^T + bias; store dtype per flag.
__global__ void gemm_out_k(const float* __restrict__ A,
                           const void* __restrict__ E,   // [N,K] = [V,D]
                           const void* __restrict__ bias,
                           void* __restrict__ Cout,
                           int M, int N, int K,
                           const int* __restrict__ flagp) {
    int bf = *flagp;
    __shared__ float As[16][65];
    __shared__ float Bs[16][65];
    int tid = threadIdx.x;
    int n0 = blockIdx.x * 64;
    int m0 = blockIdx.y * 64;
    int ty4 = (tid >> 4) << 2;
    int tx4 = (tid & 15) << 2;
    float acc[4][4] = {{0.f}};

    for (int k0 = 0; k0 < K; k0 += 16) {
#pragma unroll
        for (int r = 0; r < 4; ++r) {
            int i = r * 256 + tid;
            int ma = i >> 4, ka = i & 15;
            As[ka][ma] = A[(size_t)(m0 + ma) * K + k0 + ka];
            int nb = i >> 4, kb = i & 15;
            int col = n0 + nb;
            Bs[kb][nb] = (col < N) ? ldx(E, (size_t)col * K + k0 + kb, bf) : 0.f;
        }
        __syncthreads();
#pragma unroll
        for (int k = 0; k < 16; ++k) {
            float a0 = As[k][ty4 + 0], a1 = As[k][ty4 + 1];
            float a2 = As[k][ty4 + 2], a3 = As[k][ty4 + 3];
            float b0 = Bs[k][tx4 + 0], b1 = Bs[k][tx4 + 1];
            float b2 = Bs[k][tx4 + 2], b3 = Bs[k][tx4 + 3];
            acc[0][0] += a0 * b0; acc[0][1] += a0 * b1; acc[0][2] += a0 * b2; acc[0][3] += a0 * b3;
            acc[1][0] += a1 * b0; acc[1][1] += a1 * b1; acc[1][2] += a1 * b2; acc[1][3] += a1 * b3;
            acc[2][0] += a2 * b0; acc[2][1] += a2 * b1; acc[2][2] += a2 * b2; acc[2][3] += a2 * b3;
            acc[3][0] += a3 * b0; acc[3][1] += a3 * b1; acc[3][2] += a3 * b2; acc[3][3] += a3 * b3;
        }
        __syncthreads();
    }
#pragma unroll
    for (int i = 0; i < 4; ++i) {
#pragma unroll
        for (int j = 0; j < 4; ++j) {
            int col = n0 + tx4 + j;
            if (col < N) {
                float v = acc[i][j] + ldx(bias, col, bf);
                size_t oi = (size_t)(m0 + ty4 + i) * N + col;
                if (bf) ((__hip_bfloat16*)Cout)[oi] = __float2bfloat16(v);
                else    ((float*)Cout)[oi] = v;
            }
        }
    }
}

// Tiled attention: block = (b, h, q-tile of QT rows), one q-row per thread.
// K/V staged in LDS 64 rows at a time; inner loop reads are LDS broadcasts.
// Branchless online softmax (first processed j is always unmasked per lane).
template <int CAUSAL>
__global__ void attn_tile_k(const float* __restrict__ Q,
                            const float* __restrict__ K,
                            const float* __restrict__ V,
                            float* __restrict__ O,
                            int Sk) {
    __shared__ float Ks[TJ][DH];
    __shared__ float Vs[TJ][DH];
    int tid = threadIdx.x;
    int blk = blockIdx.x;                   // ((b*HH + h)*NQT + qt), NQT=2
    int qt = blk & 1;
    int h  = (blk >> 1) & (HH - 1);
    int b  = blk >> 4;
    int q  = qt * QT + tid;
    int wave_qmax = qt * QT + (tid | 63);   // wave-uniform

    const float* qp = Q + ((size_t)b * SS + q) * DD + h * DH;
    float4 qr[8];
#pragma unroll
    for (int i = 0; i < 8; ++i) qr[i] = ((const float4*)qp)[i];
    float4 o4[8];
#pragma unroll
    for (int i = 0; i < 8; ++i) o4[i] = make_float4(0.f, 0.f, 0.f, 0.f);
    float m = -1e30f, l = 0.f;
    const float scale = 0.17677669529663689f;  // 1/sqrt(32)

    int ntiles = CAUSAL ? ((qt + 1) * QT) / TJ : Sk / TJ;
    int r0 = tid >> 3;                      // 0..31
    int e0 = (tid & 7) * 4;                 // 0,4,..,28

    for (int t = 0; t < ntiles; ++t) {
        int j0 = t * TJ;
        // stage K/V tile: 256 threads x 2 halves cover 64 rows x 32 floats
#pragma unroll
        for (int half = 0; half < 2; ++half) {
            int r = r0 + half * 32;
            const float* kp = K + ((size_t)b * Sk + j0 + r) * DD + h * DH + e0;
            const float* vp = V + ((size_t)b * Sk + j0 + r) * DD + h * DH + e0;
            *(float4*)&Ks[r][e0] = *(const float4*)kp;
            *(float4*)&Vs[r][e0] = *(const float4*)vp;
        }
        __syncthreads();

        if (!CAUSAL || j0 <= wave_qmax) {
            int jjend = CAUSAL ? min(TJ, wave_qmax - j0 + 1) : TJ;
            for (int jj = 0; jj < jjend; ++jj) {
                float s = 0.f;
                const float4* kr = (const float4*)Ks[jj];
#pragma unroll
                for (int i = 0; i < 8; ++i) {
                    float4 kv = kr[i];
                    s += qr[i].x * kv.x + qr[i].y * kv.y + qr[i].z * kv.z + qr[i].w * kv.w;
                }
                s *= scale;
                if (CAUSAL && (j0 + jj) > q) s = -1e30f;
                float mnew = fmaxf(m, s);
                float alpha = __expf(m - mnew);   // first iter: exp(-huge)=0
                float p = __expf(s - mnew);
                l = l * alpha + p;
                const float4* vr = (const float4*)Vs[jj];
#pragma unroll
                for (int i = 0; i < 8; ++i) {
                    float4 vv = vr[i];
                    o4[i].x = o4[i].x * alpha + p * vv.x;
                    o4[i].y = o4[i].y * alpha + p * vv.y;
                    o4[i].z = o4[i].z * alpha + p * vv.z;
                    o4[i].w = o4[i].w * alpha + p * vv.w;
                }
                m = mnew;
            }
        }
        __syncthreads();
    }

    float inv = 1.f / l;
    float* op = O + ((size_t)b * SS + q) * DD + h * DH;
#pragma unroll
    for (int i = 0; i < 8; ++i) {
        float4 v = o4[i];
        ((float4*)op)[i] = make_float4(v.x * inv, v.y * inv, v.z * inv, v.w * inv);
    }
}

// x = LN(x + h); gamma/beta as element offsets from byte bases.
__global__ void add_ln_k(float* __restrict__ x,
                         const float* __restrict__ hbuf,
                         const char* __restrict__ gbase, size_t goff,
                         const char* __restrict__ bbase, size_t boff,
                         const int* __restrict__ flagp) {
    int bf = *flagp;
    const void* g = gbase + goff * (bf ? 2 : 4);
    const void* bb = bbase + boff * (bf ? 2 : 4);
    int row = blockIdx.x;
    int d = threadIdx.x;                 // 256 threads, one per element
    float v = x[(size_t)row * DD + d];
    if (hbuf) v += hbuf[(size_t)row * DD + d];
    float s = v, s2 = v * v;
#pragma unroll
    for (int off = 32; off > 0; off >>= 1) {
        s += __shfl_down(s, off);
        s2 += __shfl_down(s2, off);
    }
    __shared__ float sh[8];
    int w = d >> 6;
    if ((d & 63) == 0) { sh[w] = s; sh[4 + w] = s2; }
    __syncthreads();
    if (d == 0) {
        sh[0] = sh[0] + sh[1] + sh[2] + sh[3];
        sh[4] = sh[4] + sh[5] + sh[6] + sh[7];
    }
    __syncthreads();
    float mu = sh[0] * (1.f / DD);
    float var = fmaxf(sh[4] * (1.f / DD) - mu * mu, 0.f);
    float inv = rsqrtf(var + 1e-5f);
    x[(size_t)row * DD + d] = (v - mu) * inv * ldx(g, d, bf) + ldx(bb, d, bf);
}

extern "C" void kernel_launch(void* const* d_in, const int* in_sizes, int n_in,
                              void* d_out, int out_size, void* d_ws, size_t ws_size,
                              hipStream_t stream) {
    const void* encoded     = d_in[0];
    const int*  seq         = (const int*)d_in[1];
    const void* input_embed = d_in[2];
    const void* pos_embed   = d_in[3];
    const void* output_bias = d_in[4];
    const char* sa_qkv      = (const char*)d_in[5];
    const char* sa_o        = (const char*)d_in[6];
    const char* ca_q        = (const char*)d_in[7];
    const char* ca_kv       = (const char*)d_in[8];
    const char* ca_o        = (const char*)d_in[9];
    const char* ffn_w1      = (const char*)d_in[10];
    const char* ffn_b1      = (const char*)d_in[11];
    const char* ffn_w2      = (const char*)d_in[12];
    const char* ffn_b2      = (const char*)d_in[13];
    const char* ln_g        = (const char*)d_in[14];
    const char* ln_b        = (const char*)d_in[15];
    const char* fin_g       = (const char*)d_in[16];
    const char* fin_b       = (const char*)d_in[17];

    const size_t NTOK = (size_t)BB * SS;          // 8192

    int* flag = (int*)d_ws;
    float* x  = (float*)d_ws + 64;                // 8192*256
    float* Qb = x  + NTOK * DD;                   // 8192*256
    float* Kb = Qb + NTOK * DD;                   // 16384*256
    float* Vb = Kb + (size_t)BB * MM * DD;        // 16384*256
    float* Ob = Vb + (size_t)BB * MM * DD;        // 8192*256
    float* Tb = Qb;                               // alias: Qb dead after attn
    float* Hb = Kb;                               // alias: Kb/Vb dead after cross-attn
    // total ws: ~56 MiB

    detect_k<<<1, 256, 0, stream>>>((const unsigned int*)input_embed, flag);
    embed_k<<<NTOK, 256, 0, stream>>>(seq, input_embed, pos_embed, x, flag);

    dim3 g1(DD / 64, NTOK / 64);                  // (4,128)
    dim3 g2(DD / 64, (BB * MM) / 64);             // (4,256)
    dim3 g3(FF / 64, NTOK / 64);                  // (16,128)
    int attn_blocks = BB * HH * (SS / QT);        // 256

    for (int l = 0; l < LL; ++l) {
        size_t oQKV = (size_t)l * 3 * DD * DD;
        size_t oO   = (size_t)l * DD * DD;        // sa_o / ca_q / ca_o layer offset
        size_t oCKV = (size_t)l * 2 * DD * DD;
        size_t oW1  = (size_t)l * DD * FF;
        size_t oB1  = (size_t)l * FF;
        size_t oW2  = (size_t)l * FF * DD;
        size_t oB2  = (size_t)l * DD;
        size_t oG   = (size_t)l * 3 * DD;

        // --- self attention ---
        gemm_k<0><<<g1, 256, 0, stream>>>(x, sa_qkv, oQKV,               nullptr, 0, 0, Qb, (int)NTOK, DD, DD, 0, flag);
        gemm_k<0><<<g1, 256, 0, stream>>>(x, sa_qkv, oQKV + DD * DD,     nullptr, 0, 0, Kb, (int)NTOK, DD, DD, 0, flag);
        gemm_k<0><<<g1, 256, 0, stream>>>(x, sa_qkv, oQKV + 2 * DD * DD, nullptr, 0, 0, Vb, (int)NTOK, DD, DD, 0, flag);
        attn_tile_k<1><<<attn_blocks, 256, 0, stream>>>(Qb, Kb, Vb, Ob, SS);
        gemm_k<0><<<g1, 256, 0, stream>>>(Ob, sa_o, oO, nullptr, 0, 0, Tb, (int)NTOK, DD, DD, 0, flag);
        add_ln_k<<<NTOK, 256, 0, stream>>>(x, Tb, ln_g, oG, ln_b, oG, flag);
        // --- cross attention ---
        gemm_k<0><<<g1, 256, 0, stream>>>(x, ca_q, oO, nullptr, 0, 0, Qb, (int)NTOK, DD, DD, 0, flag);
        gemm_k<1><<<g2, 256, 0, stream>>>(encoded, ca_kv, oCKV,           nullptr, 0, 0, Kb, BB * MM, DD, DD, 0, flag);
        gemm_k<1><<<g2, 256, 0, stream>>>(encoded, ca_kv, oCKV + DD * DD, nullptr, 0, 0, Vb, BB * MM, DD, DD, 0, flag);
        attn_tile_k<0><<<attn_blocks, 256, 0, stream>>>(Qb, Kb, Vb, Ob, MM);
        gemm_k<0><<<g1, 256, 0, stream>>>(Ob, ca_o, oO, nullptr, 0, 0, Tb, (int)NTOK, DD, DD, 0, flag);
        add_ln_k<<<NTOK, 256, 0, stream>>>(x, Tb, ln_g, oG + DD, ln_b, oG + DD, flag);
        // --- FFN ---
        gemm_k<0><<<g3, 256, 0, stream>>>(x, ffn_w1, oW1, ffn_b1, oB1, 1, Hb, (int)NTOK, FF, DD, 1, flag);
        gemm_k<0><<<g1, 256, 0, stream>>>(Hb, ffn_w2, oW2, ffn_b2, oB2, 1, Tb, (int)NTOK, DD, FF, 0, flag);
        add_ln_k<<<NTOK, 256, 0, stream>>>(x, Tb, ln_g, oG + 2 * DD, ln_b, oG + 2 * DD, flag);
    }
    // final norm + shared-embedding logits
    add_ln_k<<<NTOK, 256, 0, stream>>>(x, nullptr, fin_g, 0, fin_b, 0, flag);
    dim3 g4((VV + 63) / 64, NTOK / 64);           // (47,128)
    gemm_out_k<<<g4, 256, 0, stream>>>(x, input_embed, output_bias, d_out, (int)NTOK, VV, DD, flag);
}